// Round 5
// baseline (55.714 us; speedup 1.0000x reference)
//
#include <hip/hip_runtime.h>

#define NN    2048      // number of notes
#define SEGL  32768     // max note length
#define NH    8         // harmonics
#define DURS  4194304   // output duration samples
#define TILE  1024      // output samples per block
#define BLK   256
#define SPT   (TILE / BLK)   // samples per thread = 4 -> 2 packed pairs
#define MAXC  64             // staged candidates per chunk

typedef float v2f __attribute__((ext_vector_type(2)));

__device__ __forceinline__ unsigned asu(float f) { return __float_as_uint(f); }
__device__ __forceinline__ float asf(unsigned u) { return __uint_as_float(u); }

// ---- VOP3P packed fp32 helpers; ALL sources are VGPR 64-bit pairs ---------
// (gfx950 assembler rejects single-SGPR sources for packed-f32: the operand
//  width is 64 bits, so scalars would need aligned SGPR pairs. VGPR-only is
//  always legal and has no constant-bus limits.)
__device__ __forceinline__ v2f pk_mul(v2f a, v2f b) {
    v2f d; asm("v_pk_mul_f32 %0, %1, %2" : "=v"(d) : "v"(a), "v"(b)); return d;
}
__device__ __forceinline__ v2f pk_add(v2f a, v2f b) {
    v2f d; asm("v_pk_add_f32 %0, %1, %2" : "=v"(d) : "v"(a), "v"(b)); return d;
}
__device__ __forceinline__ v2f pk_fma(v2f a, v2f b, v2f c) {
    v2f d; asm("v_pk_fma_f32 %0, %1, %2, %3" : "=v"(d) : "v"(a), "v"(b), "v"(c)); return d;
}
// a*b - c  (neg modifier on src2)
__device__ __forceinline__ v2f pk_fma_nc(v2f a, v2f b, v2f c) {
    v2f d; asm("v_pk_fma_f32 %0, %1, %2, %3 neg_lo:[0,0,1] neg_hi:[0,0,1]"
               : "=v"(d) : "v"(a), "v"(b), "v"(c)); return d;
}

__device__ __forceinline__ v2f bcast(float x) { v2f r; r.x = x; r.y = x; return r; }

__global__ __launch_bounds__(BLK) void synth_gather(
    const float* __restrict__ freq,
    const float* __restrict__ amps,
    const float* __restrict__ gainp,
    const int*  __restrict__ starts,
    const int*  __restrict__ lens,
    float* __restrict__ out)
{
    __shared__ float s_freq[MAXC];
    __shared__ int   s_start[MAXC];
    __shared__ int   s_len[MAXC];

    const int tile_lo = (int)blockIdx.x * TILE;
    const int tile_hi = tile_lo + TILE;

    // Candidate notes = contiguous range [j0, j1) in the sorted start array.
    int lo = 0, hi = NN;
    const int v0 = tile_lo - SEGL;
    while (lo < hi) { int m = (lo + hi) >> 1; if (starts[m] > v0) hi = m; else lo = m + 1; }
    const int j0 = lo;
    lo = 0; hi = NN;
    while (lo < hi) { int m = (lo + hi) >> 1; if (starts[m] >= tile_hi) hi = m; else lo = m + 1; }
    const int j1 = lo;

    // Broadcast uniform constants into VGPR pairs.
    v2f a2[NH];
#pragma unroll
    for (int h = 0; h < NH; ++h) a2[h] = bcast(amps[h]);
    const v2f kg2    = bcast(gainp[0] * 2.8853900817779268f);  // 2*log2(e)
    const v2f invpi2 = bcast(0.31830988618379067f);
    const v2f magic2 = bcast(12582912.0f);                      // 1.5*2^23
    const v2f nmag2  = bcast(-12582912.0f);
    const v2f npihi2 = bcast(-0x1.921FB6p+1f);                  // -fp32(pi)
    const v2f pimid2 = bcast(8.7422777e-8f);                    // -(pi - pi_hi)
    const v2f one2   = bcast(1.0f);
    const v2f sc11 = bcast(-2.5052108e-8f), sc9 = bcast(2.7557319e-6f);
    const v2f sc7  = bcast(-1.9841270e-4f), sc5 = bcast(8.3333333e-3f);
    const v2f sc3  = bcast(-1.6666667e-1f);
    const v2f cc10 = bcast(-2.7557319e-7f), cc8 = bcast(2.4801587e-5f);
    const v2f cc6  = bcast(-1.3888889e-3f), cc4 = bcast(4.1666668e-2f);
    const v2f cc2  = bcast(-0.5f);

    v2f acc[SPT / 2];
#pragma unroll
    for (int p = 0; p < SPT / 2; ++p) acc[p] = (v2f){0.0f, 0.0f};

    const int base = tile_lo + (int)threadIdx.x;

    for (int jb = j0; jb < j1; jb += MAXC) {
        const int cchunk = min(j1 - jb, MAXC);
        __syncthreads();
        for (int c = (int)threadIdx.x; c < cchunk; c += BLK) {
            int j = jb + c;
            s_freq[c] = freq[j];
            int st = starts[j];
            int ln = lens[j];
            int rem = DURS - st;          // out_len = min(start+len, dur) - start
            if (rem < 0) rem = 0;
            if (ln > rem) ln = rem;
            if (ln < 0) ln = 0;
            s_start[c] = st;
            s_len[c] = ln;
        }
        __syncthreads();

        for (int c = 0; c < cchunk; ++c) {
            const v2f fr2 = bcast(s_freq[c]);
            const int st = s_start[c];
            const int ln = s_len[c];
            const int tof = base - st;
#pragma unroll
            for (int p = 0; p < SPT / 2; ++p) {
                const int t0 = tof + (2 * p) * BLK;
                const int t1 = t0 + BLK;
                const bool vld0 = (unsigned)t0 < (unsigned)ln;
                const bool vld1 = (unsigned)t1 < (unsigned)ln;
                if (vld0 || vld1) {
                    v2f tf; tf.x = (float)t0; tf.y = (float)t1;
                    // phase = fp32(freq*t): identical rounding to reference
                    v2f ph = pk_mul(tf, fr2);
                    // range reduction mod pi (magic round-to-nearest-even)
                    v2f kf = pk_fma(ph, invpi2, magic2);
                    unsigned sg0 = asu(kf.x) << 31;     // parity of k -> sign bit
                    unsigned sg1 = asu(kf.y) << 31;
                    v2f kq = pk_add(kf, nmag2);
                    v2f r  = pk_fma(kq, npihi2, ph);
                    r = pk_fma(kq, pimid2, r);
                    v2f y = pk_mul(r, r);
                    // sin poly
                    v2f sp = pk_fma(y, sc11, sc9);
                    sp = pk_fma(y, sp, sc7);
                    sp = pk_fma(y, sp, sc5);
                    sp = pk_fma(y, sp, sc3);
                    v2f ry = pk_mul(r, y);
                    v2f s1 = pk_fma(ry, sp, r);
                    // cos poly
                    v2f cp = pk_fma(y, cc10, cc8);
                    cp = pk_fma(y, cp, cc6);
                    cp = pk_fma(y, cp, cc4);
                    cp = pk_fma(y, cp, cc2);
                    v2f c1 = pk_fma(y, cp, one2);
                    // apply (-1)^k to both -> true sin/cos of the phase
                    s1.x = asf(asu(s1.x) ^ sg0);  s1.y = asf(asu(s1.y) ^ sg1);
                    c1.x = asf(asu(c1.x) ^ sg0);  c1.y = asf(asu(c1.y) ^ sg1);
                    // Chebyshev: s_{h+1} = 2c*s_h - s_{h-1}
                    v2f tc = pk_add(c1, c1);
                    v2f s2 = pk_mul(tc, s1);
                    v2f s3 = pk_fma_nc(tc, s2, s1);
                    v2f s4 = pk_fma_nc(tc, s3, s2);
                    v2f s5 = pk_fma_nc(tc, s4, s3);
                    v2f s6 = pk_fma_nc(tc, s5, s4);
                    v2f s7 = pk_fma_nc(tc, s6, s5);
                    v2f s8 = pk_fma_nc(tc, s7, s6);
                    v2f seg = pk_mul(s1, a2[0]);
                    seg = pk_fma(s2, a2[1], seg);
                    seg = pk_fma(s3, a2[2], seg);
                    seg = pk_fma(s4, a2[3], seg);
                    seg = pk_fma(s5, a2[4], seg);
                    seg = pk_fma(s6, a2[5], seg);
                    seg = pk_fma(s7, a2[6], seg);
                    seg = pk_fma(s8, a2[7], seg);
                    // tanh(g*x) = 1 - 2/(exp2(kg*x)+1)
                    v2f sx = pk_mul(seg, kg2);
                    float e0 = __builtin_amdgcn_exp2f(sx.x);
                    float e1 = __builtin_amdgcn_exp2f(sx.y);
                    float rc0 = __builtin_amdgcn_rcpf(e0 + 1.0f);
                    float rc1 = __builtin_amdgcn_rcpf(e1 + 1.0f);
                    float g0 = fmaf(-2.0f, rc0, 1.0f);
                    float g1 = fmaf(-2.0f, rc1, 1.0f);
                    g0 = vld0 ? g0 : 0.0f;
                    g1 = vld1 ? g1 : 0.0f;
                    v2f g; g.x = g0; g.y = g1;
                    acc[p] = pk_add(acc[p], g);
                }
            }
        }
    }

#pragma unroll
    for (int p = 0; p < SPT / 2; ++p) {
        out[base + (2 * p) * BLK]     = acc[p].x;
        out[base + (2 * p + 1) * BLK] = acc[p].y;
    }
}

extern "C" void kernel_launch(void* const* d_in, const int* in_sizes, int n_in,
                              void* d_out, int out_size, void* d_ws, size_t ws_size,
                              hipStream_t stream) {
    const float* freq   = (const float*)d_in[0];
    const float* amps   = (const float*)d_in[1];
    const float* gain   = (const float*)d_in[2];
    const int*   starts = (const int*)d_in[3];
    const int*   lens   = (const int*)d_in[4];
    float* out = (float*)d_out;

    const int grid = DURS / TILE;   // 4096 blocks
    synth_gather<<<grid, BLK, 0, stream>>>(freq, amps, gain, starts, lens, out);
}

// Round 6
// 42.037 us; speedup vs baseline: 1.3253x; 1.3253x over previous
//
#include <hip/hip_runtime.h>

#define NN    2048      // number of notes
#define SEGL  32768     // max note length
#define NH    8         // harmonics
#define DURS  4194304   // output duration samples
#define TILE  512       // output samples per block (fine for dynamic balance)
#define BLK   256
#define SPT   (TILE / BLK)   // samples per thread = 2
#define MAXC  64             // staged candidates per chunk (expected ~16)

// ---- accurate sincos for |x| < ~2^18 --------------------------------------
// One Cody-Waite reduction mod pi; sin deg-7 / cos deg-8 Taylor on [-pi/2,pi/2]
// (errors 1.6e-4 / 2.5e-5 rad-equiv -- far below the dominant harmonic-arg
// rounding mismatch vs the reference); sign (-1)^k applied to both via xor so
// the Chebyshev recurrence yields correctly-signed sin(h*x).
__device__ __forceinline__ void sincos_acc(float x, float& s_out, float& c_out) {
    const float INV_PI = 0.31830988618379067f;
    float kq = rintf(x * INV_PI);
    float r = fmaf(kq, -0x1.921FB6p+1f, x);     // pi_hi = fp32(pi), exact in fma
    r = fmaf(kq, 8.7422777e-8f, r);             // pi_mid = -(pi - pi_hi)
    int ki = (int)kq;
    unsigned sgn = ((unsigned)ki) << 31;        // bit31 = parity of k
    float y = r * r;
    // sin(r): r + r*y*(-1/6 + y*(1/120 - y/5040))
    float sp = fmaf(y, -1.9841270e-4f, 8.3333333e-3f);
    sp = fmaf(y, sp, -1.6666667e-1f);
    float s = fmaf(r * y, sp, r);
    // cos(r): 1 + y*(-1/2 + y*(1/24 + y*(-1/720 + y/40320)))
    float cp = fmaf(y, 2.4801587e-5f, -1.3888889e-3f);
    cp = fmaf(y, cp, 4.1666668e-2f);
    cp = fmaf(y, cp, -0.5f);
    float c = fmaf(y, cp, 1.0f);
    s_out = __uint_as_float(__float_as_uint(s) ^ sgn);
    c_out = __uint_as_float(__float_as_uint(c) ^ sgn);
}

__global__ __launch_bounds__(BLK) void synth_gather(
    const float* __restrict__ freq,
    const float* __restrict__ amps,
    const float* __restrict__ gainp,
    const int*  __restrict__ starts,
    const int*  __restrict__ lens,
    float* __restrict__ out)
{
    __shared__ float s_freq[MAXC];
    __shared__ int   s_start[MAXC];
    __shared__ int   s_len[MAXC];

    const int tile_lo = (int)blockIdx.x * TILE;
    const int tile_hi = tile_lo + TILE;

    // Candidate notes = contiguous range [j0, j1) in the sorted start array.
    int lo = 0, hi = NN;
    const int v0 = tile_lo - SEGL;
    while (lo < hi) { int m = (lo + hi) >> 1; if (starts[m] > v0) hi = m; else lo = m + 1; }
    const int j0 = lo;
    lo = 0; hi = NN;
    while (lo < hi) { int m = (lo + hi) >> 1; if (starts[m] >= tile_hi) hi = m; else lo = m + 1; }
    const int j1 = lo;

    float a[NH];
#pragma unroll
    for (int h = 0; h < NH; ++h) a[h] = amps[h];
    // tanh(g*x) = 1 - 2/(exp2(x * (2*g*log2e)) + 1)
    const float kg = gainp[0] * 2.8853900817779268f;   // 2*log2(e)

    float acc[SPT];
#pragma unroll
    for (int k = 0; k < SPT; ++k) acc[k] = 0.0f;

    const int base = tile_lo + (int)threadIdx.x;

    for (int jb = j0; jb < j1; jb += MAXC) {
        const int cchunk = min(j1 - jb, MAXC);
        __syncthreads();
        for (int c = (int)threadIdx.x; c < cchunk; c += BLK) {
            int j = jb + c;
            s_freq[c] = freq[j];
            int st = starts[j];
            int ln = lens[j];
            int rem = DURS - st;          // out_len = min(start+len, dur) - start
            if (rem < 0) rem = 0;
            if (ln > rem) ln = rem;
            if (ln < 0) ln = 0;
            s_start[c] = st;
            s_len[c] = ln;
        }
        __syncthreads();

        for (int c = 0; c < cchunk; ++c) {
            const float fr = s_freq[c];
            const int st = s_start[c];
            const int ln = s_len[c];
            const int tof = base - st;
            const float tf0 = (float)tof;     // exact: |tof| < 2^24
#pragma unroll
            for (int k = 0; k < SPT; ++k) {
                const int t = tof + k * BLK;
                if ((unsigned)t < (unsigned)ln) {
                    const float tf = tf0 + (float)(k * BLK);   // exact fp32 int
                    // phase = fp32(freq*t): identical rounding to reference
                    const float ph = fr * tf;
                    float s1, c1;
                    sincos_acc(ph, s1, c1);
                    const float tc = c1 + c1;
                    // Chebyshev: s_{h+1} = 2c*s_h - s_{h-1}
                    const float s2 = tc * s1;
                    const float s3 = fmaf(tc, s2, -s1);
                    const float s4 = fmaf(tc, s3, -s2);
                    const float s5 = fmaf(tc, s4, -s3);
                    const float s6 = fmaf(tc, s5, -s4);
                    const float s7 = fmaf(tc, s6, -s5);
                    const float s8 = fmaf(tc, s7, -s6);
                    float seg = a[0] * s1;
                    seg = fmaf(a[1], s2, seg);
                    seg = fmaf(a[2], s3, seg);
                    seg = fmaf(a[3], s4, seg);
                    seg = fmaf(a[4], s5, seg);
                    seg = fmaf(a[5], s6, seg);
                    seg = fmaf(a[6], s7, seg);
                    seg = fmaf(a[7], s8, seg);
                    const float e = __builtin_amdgcn_exp2f(seg * kg);
                    const float rc = __builtin_amdgcn_rcpf(e + 1.0f);
                    acc[k] += fmaf(-2.0f, rc, 1.0f);
                }
            }
        }
    }

#pragma unroll
    for (int k = 0; k < SPT; ++k) {
        out[base + k * BLK] = acc[k];
    }
}

extern "C" void kernel_launch(void* const* d_in, const int* in_sizes, int n_in,
                              void* d_out, int out_size, void* d_ws, size_t ws_size,
                              hipStream_t stream) {
    const float* freq   = (const float*)d_in[0];
    const float* amps   = (const float*)d_in[1];
    const float* gain   = (const float*)d_in[2];
    const int*   starts = (const int*)d_in[3];
    const int*   lens   = (const int*)d_in[4];
    float* out = (float*)d_out;

    const int grid = DURS / TILE;   // 8192 blocks -> 32/CU, 8 co-resident
    synth_gather<<<grid, BLK, 0, stream>>>(freq, amps, gain, starts, lens, out);
}

// Round 7
// 38.489 us; speedup vs baseline: 1.4475x; 1.0922x over previous
//
#include <hip/hip_runtime.h>

#define NN    2048      // number of notes
#define SEGL  32768     // max note length
#define NH    8         // harmonics
#define DURS  4194304   // output duration samples
#define TILE  512       // output samples per block
#define BLK   256
#define SPT   (TILE / BLK)   // samples per thread = 2
#define MAXC  64             // staged candidates per chunk (expected ~16)

// Per-pair math: theta = fp32(freq*t) (reference-rounded); reduce mod pi;
// s_r = sin(r) [deg-7], u_r = 2*cos(r) [deg-8, pre-doubled]; apply (-1)^k to
// both; then  tanh_arg = sin(theta) * Qk(2*cos(theta))  where Qk is the
// degree-7 Chebyshev-U combination of the 8 harmonic amps, pre-scaled by
// 2*gain*log2(e). One Horner chain replaces the old recurrence + dot product.
__global__ __launch_bounds__(BLK) void synth_gather(
    const float* __restrict__ freq,
    const float* __restrict__ amps,
    const float* __restrict__ gainp,
    const int*  __restrict__ starts,
    const int*  __restrict__ lens,
    float* __restrict__ out)
{
    __shared__ float s_freq[MAXC];
    __shared__ int   s_start[MAXC];
    __shared__ int   s_len[MAXC];

    const int tile_lo = (int)blockIdx.x * TILE;
    const int tile_hi = tile_lo + TILE;

    // Candidate notes = contiguous range [j0, j1) in the sorted start array.
    int lo = 0, hi = NN;
    const int v0 = tile_lo - SEGL;
    while (lo < hi) { int m = (lo + hi) >> 1; if (starts[m] > v0) hi = m; else lo = m + 1; }
    const int j0 = lo;
    lo = 0; hi = NN;
    while (lo < hi) { int m = (lo + hi) >> 1; if (starts[m] >= tile_hi) hi = m; else lo = m + 1; }
    const int j1 = lo;

    // ---- one-time: Chebyshev-U basis change, pre-scaled by 2*g*log2(e) ----
    const float a0 = amps[0], a1 = amps[1], a2 = amps[2], a3 = amps[3];
    const float a4 = amps[4], a5 = amps[5], a6 = amps[6], a7 = amps[7];
    const float kg = gainp[0] * 2.8853900817779268f;   // 2*log2(e)
    const float b7 = kg * a7;
    const float b6 = kg * a6;
    const float b5 = kg * (a5 - 6.0f * a7);
    const float b4 = kg * (a4 - 5.0f * a6);
    const float b3 = kg * (a3 - 4.0f * a5 + 10.0f * a7);
    const float b2 = kg * (a2 - 3.0f * a4 + 6.0f * a6);
    const float b1 = kg * (a1 - 2.0f * a3 + 3.0f * a5 - 4.0f * a7);
    const float b0 = kg * (a0 - a2 + a4 - a6);

    float acc[SPT];
#pragma unroll
    for (int k = 0; k < SPT; ++k) acc[k] = 0.0f;

    const int base = tile_lo + (int)threadIdx.x;

    for (int jb = j0; jb < j1; jb += MAXC) {
        const int cchunk = min(j1 - jb, MAXC);
        __syncthreads();
        for (int c = (int)threadIdx.x; c < cchunk; c += BLK) {
            int j = jb + c;
            s_freq[c] = freq[j];
            int st = starts[j];
            int ln = lens[j];
            int rem = DURS - st;          // out_len = min(start+len, dur) - start
            if (rem < 0) rem = 0;
            if (ln > rem) ln = rem;
            if (ln < 0) ln = 0;
            s_start[c] = st;
            s_len[c] = ln;
        }
        __syncthreads();

        for (int c = 0; c < cchunk; ++c) {
            const float fr = s_freq[c];
            const int st = s_start[c];
            const int ln = s_len[c];
            const int tof = base - st;
            const float tf0 = (float)tof;     // exact: |tof| < 2^24
#pragma unroll
            for (int k = 0; k < SPT; ++k) {
                const int t = tof + k * BLK;
                if ((unsigned)t < (unsigned)ln) {
                    const float tf = tf0 + (float)(k * BLK);   // exact fp32 int
                    // theta = fp32(freq*t): identical rounding to reference
                    const float ph = fr * tf;
                    // ---- reduction mod pi ----
                    const float kq = rintf(ph * 0.31830988618379067f);
                    float r = fmaf(kq, -0x1.921FB6p+1f, ph);   // pi_hi exact in fma
                    r = fmaf(kq, 8.7422777e-8f, r);            // -(pi - pi_hi)
                    const unsigned sgn = ((unsigned)(int)kq) << 31;
                    const float y = r * r;
                    // sin(r), deg 7
                    float sp = fmaf(y, -1.9841270e-4f, 8.3333333e-3f);
                    sp = fmaf(y, sp, -1.6666667e-1f);
                    float s1 = fmaf(r * y, sp, r);
                    // 2*cos(r), deg 8 (coefficients pre-doubled)
                    float cp = fmaf(y, 4.9603175e-5f, -2.7777778e-3f);
                    cp = fmaf(y, cp, 8.3333333e-2f);
                    cp = fmaf(y, cp, -1.0f);
                    float u = fmaf(y, cp, 2.0f);
                    // apply (-1)^k to both -> sin(theta), 2*cos(theta)
                    s1 = __uint_as_float(__float_as_uint(s1) ^ sgn);
                    u  = __uint_as_float(__float_as_uint(u) ^ sgn);
                    // Horner: q = kg * Q(u)
                    float q = fmaf(u, b7, b6);
                    q = fmaf(u, q, b5);
                    q = fmaf(u, q, b4);
                    q = fmaf(u, q, b3);
                    q = fmaf(u, q, b2);
                    q = fmaf(u, q, b1);
                    q = fmaf(u, q, b0);
                    // tanh(gain*seg) = 1 - 2/(exp2(s1*q)+1)
                    const float e = __builtin_amdgcn_exp2f(s1 * q);
                    const float rc = __builtin_amdgcn_rcpf(e + 1.0f);
                    acc[k] += fmaf(-2.0f, rc, 1.0f);
                }
            }
        }
    }

#pragma unroll
    for (int k = 0; k < SPT; ++k) {
        out[base + k * BLK] = acc[k];
    }
}

extern "C" void kernel_launch(void* const* d_in, const int* in_sizes, int n_in,
                              void* d_out, int out_size, void* d_ws, size_t ws_size,
                              hipStream_t stream) {
    const float* freq   = (const float*)d_in[0];
    const float* amps   = (const float*)d_in[1];
    const float* gain   = (const float*)d_in[2];
    const int*   starts = (const int*)d_in[3];
    const int*   lens   = (const int*)d_in[4];
    float* out = (float*)d_out;

    const int grid = DURS / TILE;   // 8192 blocks -> 32/CU, 8 co-resident
    synth_gather<<<grid, BLK, 0, stream>>>(freq, amps, gain, starts, lens, out);
}

// Round 8
// 36.672 us; speedup vs baseline: 1.5192x; 1.0495x over previous
//
#include <hip/hip_runtime.h>

#define NN    2048      // number of notes
#define SEGL  32768     // max note length
#define NH    8         // harmonics
#define DURS  4194304   // output duration samples
#define BLK   128
#define S     8                 // consecutive samples per thread
#define TILE  (BLK * S)         // 1024
#define MAXC  64                // staged candidates per chunk (expected ~16)

// accurate sincos (|x| < 2^18): Cody-Waite mod pi + deg-7/deg-8 Taylor,
// (-1)^k sign applied to both via xor.
__device__ __forceinline__ void sincos_acc(float x, float& s_out, float& c_out) {
    const float kq = rintf(x * 0.31830988618379067f);
    float r = fmaf(kq, -0x1.921FB6p+1f, x);     // pi_hi = fp32(pi), exact in fma
    r = fmaf(kq, 8.7422777e-8f, r);             // -(pi - pi_hi)
    const unsigned sgn = ((unsigned)(int)kq) << 31;
    const float y = r * r;
    float sp = fmaf(y, -1.9841270e-4f, 8.3333333e-3f);
    sp = fmaf(y, sp, -1.6666667e-1f);
    float s = fmaf(r * y, sp, r);
    float cp = fmaf(y, 2.4801587e-5f, -1.3888889e-3f);
    cp = fmaf(y, cp, 4.1666668e-2f);
    cp = fmaf(y, cp, -0.5f);
    float c = fmaf(y, cp, 1.0f);
    s_out = __uint_as_float(__float_as_uint(s) ^ sgn);
    c_out = __uint_as_float(__float_as_uint(c) ^ sgn);
}

__global__ __launch_bounds__(BLK) void synth_gather(
    const float* __restrict__ freq,
    const float* __restrict__ amps,
    const float* __restrict__ gainp,
    const int*  __restrict__ starts,
    const int*  __restrict__ lens,
    float* __restrict__ out)
{
    __shared__ float4 s_cand[MAXC];   // {freq, start(bits), len(bits), -}

    const int tile_lo = (int)blockIdx.x * TILE;
    const int tile_hi = tile_lo + TILE;

    // Candidate notes = contiguous range [j0, j1) in the sorted start array.
    int lo = 0, hi = NN;
    const int v0 = tile_lo - SEGL;
    while (lo < hi) { int m = (lo + hi) >> 1; if (starts[m] > v0) hi = m; else lo = m + 1; }
    const int j0 = lo;
    lo = 0; hi = NN;
    while (lo < hi) { int m = (lo + hi) >> 1; if (starts[m] >= tile_hi) hi = m; else lo = m + 1; }
    const int j1 = lo;

    // Chebyshev-U basis combination of amps, pre-scaled by 2*g*log2(e),
    // then rebased to Horner-in-cos: bt_k = b_k * 2^k.
    const float a0 = amps[0], a1 = amps[1], a2 = amps[2], a3 = amps[3];
    const float a4 = amps[4], a5 = amps[5], a6 = amps[6], a7 = amps[7];
    const float kg = gainp[0] * 2.8853900817779268f;   // 2*log2(e)
    const float bt7 = kg * a7 * 128.0f;
    const float bt6 = kg * a6 * 64.0f;
    const float bt5 = kg * (a5 - 6.0f * a7) * 32.0f;
    const float bt4 = kg * (a4 - 5.0f * a6) * 16.0f;
    const float bt3 = kg * (a3 - 4.0f * a5 + 10.0f * a7) * 8.0f;
    const float bt2 = kg * (a2 - 3.0f * a4 + 6.0f * a6) * 4.0f;
    const float bt1 = kg * (a1 - 2.0f * a3 + 3.0f * a5 - 4.0f * a7) * 2.0f;
    const float bt0 = kg * (a0 - a2 + a4 - a6);

    float acc[S];
#pragma unroll
    for (int i = 0; i < S; ++i) acc[i] = 0.0f;

    const int base = tile_lo + (int)threadIdx.x * S;

    for (int jb = j0; jb < j1; jb += MAXC) {
        const int cchunk = min(j1 - jb, MAXC);
        __syncthreads();
        for (int c = (int)threadIdx.x; c < cchunk; c += BLK) {
            int j = jb + c;
            int st = starts[j];
            int ln = lens[j];
            int rem = DURS - st;          // out_len = min(start+len, dur) - start
            if (rem < 0) rem = 0;
            if (ln > rem) ln = rem;
            if (ln < 0) ln = 0;
            float4 v;
            v.x = freq[j];
            v.y = __int_as_float(st);
            v.z = __int_as_float(ln);
            v.w = 0.0f;
            s_cand[c] = v;
        }
        __syncthreads();

        for (int c = 0; c < cchunk; ++c) {
            const float4 v = s_cand[c];
            const float fr = v.x;
            const int st = __float_as_int(v.y);
            const int ln = __float_as_int(v.z);
            const int t0 = base - st;
            // this thread's run [t0, t0+S) vs valid [0, ln)
            if (t0 >= ln || t0 + (S - 1) < 0) continue;

            const float tf0 = (float)t0;
            const float ph0 = fr * tf0;       // matches reference fp32 arg at i=0
            float s, cc;
            sincos_acc(ph0, s, cc);
            // per-step rotation coefficients: sin(fr), cos(fr); fr in [0,1) -> no reduction
            const float y = fr * fr;
            float sp = fmaf(y, -1.9841270e-4f, 8.3333333e-3f);
            sp = fmaf(y, sp, -1.6666667e-1f);
            const float sd = fmaf(fr * y, sp, fr);
            float cp = fmaf(y, 2.4801587e-5f, -1.3888889e-3f);
            cp = fmaf(y, cp, 4.1666668e-2f);
            cp = fmaf(y, cp, -0.5f);
            const float cd = fmaf(y, cp, 1.0f);

            if (t0 >= 0 && t0 + S <= ln) {
                // full-cover fast path: no per-sample validity checks
#pragma unroll
                for (int i = 0; i < S; ++i) {
                    float q = fmaf(cc, bt7, bt6);
                    q = fmaf(cc, q, bt5);
                    q = fmaf(cc, q, bt4);
                    q = fmaf(cc, q, bt3);
                    q = fmaf(cc, q, bt2);
                    q = fmaf(cc, q, bt1);
                    q = fmaf(cc, q, bt0);
                    const float e = __builtin_amdgcn_exp2f(s * q);
                    const float rc = __builtin_amdgcn_rcpf(e + 1.0f);
                    acc[i] += fmaf(-2.0f, rc, 1.0f);
                    const float sn = fmaf(cc, sd, s * cd);   // advance rotation
                    cc = fmaf(-s, sd, cc * cd);
                    s = sn;
                }
            } else {
                // boundary path: per-sample mask
#pragma unroll
                for (int i = 0; i < S; ++i) {
                    float q = fmaf(cc, bt7, bt6);
                    q = fmaf(cc, q, bt5);
                    q = fmaf(cc, q, bt4);
                    q = fmaf(cc, q, bt3);
                    q = fmaf(cc, q, bt2);
                    q = fmaf(cc, q, bt1);
                    q = fmaf(cc, q, bt0);
                    const float e = __builtin_amdgcn_exp2f(s * q);
                    const float rc = __builtin_amdgcn_rcpf(e + 1.0f);
                    const float term = fmaf(-2.0f, rc, 1.0f);
                    const bool valid = (unsigned)(t0 + i) < (unsigned)ln;
                    acc[i] += valid ? term : 0.0f;
                    const float sn = fmaf(cc, sd, s * cd);
                    cc = fmaf(-s, sd, cc * cd);
                    s = sn;
                }
            }
        }
    }

#pragma unroll
    for (int i = 0; i < S; i += 4) {
        float4 o;
        o.x = acc[i]; o.y = acc[i + 1]; o.z = acc[i + 2]; o.w = acc[i + 3];
        *reinterpret_cast<float4*>(&out[base + i]) = o;
    }
}

extern "C" void kernel_launch(void* const* d_in, const int* in_sizes, int n_in,
                              void* d_out, int out_size, void* d_ws, size_t ws_size,
                              hipStream_t stream) {
    const float* freq   = (const float*)d_in[0];
    const float* amps   = (const float*)d_in[1];
    const float* gain   = (const float*)d_in[2];
    const int*   starts = (const int*)d_in[3];
    const int*   lens   = (const int*)d_in[4];
    float* out = (float*)d_out;

    const int grid = DURS / TILE;   // 4096 blocks
    synth_gather<<<grid, BLK, 0, stream>>>(freq, amps, gain, starts, lens, out);
}